// Round 9
// baseline (261.412 us; speedup 1.0000x reference)
//
#include <hip/hip_runtime.h>
#include <hip/hip_bf16.h>
#include <stdint.h>

// B=2, S=2048, D=1024, H=16, HD=64. Inputs fp32, d_out fp32 (resolved r1-r3).
// canon fp32->bf16 -> QKV GEMM (Q pre-scaled by 0.125*log2e; V transposed
// [B,H,HD,S]) -> flash attn (32x32 MFMA, kv-split 2-way, no-max exp2 softmax,
// r9: K/V LDS in [quarter][row][16el] form -> 32B row stride -> all-32-bank
// b128 reads, conflict-free) -> out-proj GEMM (r9: 128x64 tile, BK=64,
// 512 blocks, conflict-free [khalf][row][32] LDS).
#define Bb 2
#define Ss 2048
#define Dd 1024
#define Hh 16
#define HD 64

typedef __attribute__((ext_vector_type(8))) __bf16 bf16x8;
typedef __attribute__((ext_vector_type(4))) __bf16 bf16x4;
typedef __attribute__((ext_vector_type(2))) __bf16 bf16x2;
typedef __attribute__((ext_vector_type(4))) float f32x4;
typedef __attribute__((ext_vector_type(16))) float f32x16;

#define LOG2E 1.44269504088896f
#define SCL2 (0.125f * LOG2E)

// ---- workspace layout (bf16 elements) --------------------------------------
#define HS_N   (Bb * Ss * Dd)
#define W_N    (Dd * Dd)
#define B_N    (Dd)
#define CAN_HS 0
#define CAN_WQ (CAN_HS + HS_N)
#define CAN_BQ (CAN_WQ + W_N)
#define CAN_WK (CAN_BQ + B_N)
#define CAN_BK (CAN_WK + W_N)
#define CAN_WV (CAN_BK + B_N)
#define CAN_BV (CAN_WV + W_N)
#define CAN_WO (CAN_BV + B_N)
#define CAN_BO (CAN_WO + W_N)
#define CAN_END (CAN_BO + B_N)
#define TSZ    (Bb * Hh * Ss * HD)
#define WS_ELEMS (CAN_END + 4 * TSZ)
#define WS_NEED ((size_t)WS_ELEMS * 2)

__device__ __forceinline__ void gl_lds16(const __bf16* g, __bf16* l) {
  __builtin_amdgcn_global_load_lds(
      (const __attribute__((address_space(1))) void*)g,
      (__attribute__((address_space(3))) void*)l,
      16, 0, 0);
}

__device__ __forceinline__ void cfence() { asm volatile("" ::: "memory"); }

// fp32 -> bf16 canonicalization (segment table; r4 postmortem).
__global__ void canon_kernel(const float* hs, const float* Wq, const float* bq,
                             const float* Wk, const float* bk, const float* Wv,
                             const float* bv, const float* Wo, const float* bo,
                             __bf16* __restrict__ dst) {
  const float* srcs[9] = {hs, Wq, bq, Wk, bk, Wv, bv, Wo, bo};
  const long starts[10] = {CAN_HS, CAN_WQ, CAN_BQ, CAN_WK, CAN_BK,
                           CAN_WV, CAN_BV, CAN_WO, CAN_BO, CAN_END};
  const long nchunks = CAN_END / 8;
  for (long c = blockIdx.x * blockDim.x + threadIdx.x; c < nchunks;
       c += (long)gridDim.x * blockDim.x) {
    const long i = c * 8;
    int seg = 0;
#pragma unroll
    for (int t = 1; t < 9; t++) seg += (i >= starts[t]) ? 1 : 0;
    const float* s = srcs[seg] + (i - starts[seg]);
    bf16x8 v;
#pragma unroll
    for (int e = 0; e < 8; e++) v[e] = (__bf16)s[e];
    *(bf16x8*)(dst + i) = v;
  }
}

// ---------------------------------------------------------------------------
// QKV GEMM: C[4096, 1024 x3] = A @ W^T + bias (bf16). 128x128 tile, BK=32.
// Q (pre-scaled by SCL2), K -> [B,H,S,HD]; V -> transposed [B,H,HD,S].
// ---------------------------------------------------------------------------
__global__ __launch_bounds__(256, 2) void gemm_qkv(
    const __bf16* __restrict__ A,
    const __bf16* __restrict__ W0, const __bf16* __restrict__ W1,
    const __bf16* __restrict__ W2,
    const __bf16* __restrict__ b0, const __bf16* __restrict__ b1,
    const __bf16* __restrict__ b2,
    __bf16* __restrict__ O0, __bf16* __restrict__ O1, __bf16* __restrict__ O2) {
  __shared__ __align__(16) __bf16 sA[128 * 32];
  __shared__ __align__(16) __bf16 sB[128 * 32];
  const int tid = threadIdx.x;
  const int lane = tid & 63;
  const int wid = tid >> 6;
  const int quad = lane >> 4;
  const int l15 = lane & 15;
  const int mBlock = blockIdx.x * 128;

  const int which = blockIdx.y >> 3;  // 0:Q 1:K 2:V
  const int nBlock = (blockIdx.y & 7) * 128;
  const __bf16* W = which == 0 ? W0 : (which == 1 ? W1 : W2);
  const __bf16* bias = which == 0 ? b0 : (which == 1 ? b1 : b2);
  __bf16* Out = which == 0 ? O0 : (which == 1 ? O1 : O2);

  const int waveM = (wid >> 1) * 64;
  const int waveN = (wid & 1) * 64;

  f32x4 acc[4][4] = {};

  const int c1 = wid * 64 + lane;
  const int c2 = c1 + 256;
  const __bf16* Ar1 = A + (mBlock + (c1 >> 2)) * Dd + (c1 & 3) * 8;
  const __bf16* Ar2 = A + (mBlock + (c2 >> 2)) * Dd + (c2 & 3) * 8;
  const __bf16* Wr1 = W + (nBlock + (c1 >> 2)) * Dd + (c1 & 3) * 8;
  const __bf16* Wr2 = W + (nBlock + (c2 >> 2)) * Dd + (c2 & 3) * 8;
  __bf16* ldsA1 = sA + c1 * 8;
  __bf16* ldsA2 = sA + c2 * 8;
  __bf16* ldsB1 = sB + c1 * 8;
  __bf16* ldsB2 = sB + c2 * 8;

  for (int k0 = 0; k0 < Dd; k0 += 32) {
    gl_lds16(Ar1 + k0, ldsA1);
    gl_lds16(Ar2 + k0, ldsA2);
    gl_lds16(Wr1 + k0, ldsB1);
    gl_lds16(Wr2 + k0, ldsB2);
    __syncthreads();

    bf16x8 aF[4], bF[4];
#pragma unroll
    for (int mi = 0; mi < 4; mi++)
      aF[mi] = *(const bf16x8*)(sA + (waveM + mi * 16 + l15) * 32 + quad * 8);
#pragma unroll
    for (int ni = 0; ni < 4; ni++)
      bF[ni] = *(const bf16x8*)(sB + (waveN + ni * 16 + l15) * 32 + quad * 8);
#pragma unroll
    for (int mi = 0; mi < 4; mi++)
#pragma unroll
      for (int ni = 0; ni < 4; ni++)
        acc[mi][ni] = __builtin_amdgcn_mfma_f32_16x16x32_bf16(
            aF[mi], bF[ni], acc[mi][ni], 0, 0, 0);
    __syncthreads();
  }

  // C/D layout: col = lane&15, row = quad*4 + r.
#pragma unroll
  for (int ni = 0; ni < 4; ni++) {
    const int ng = nBlock + waveN + ni * 16 + l15;
    const float bv = (float)bias[ng];
#pragma unroll
    for (int mi = 0; mi < 4; mi++) {
      const int mg0 = mBlock + waveM + mi * 16 + quad * 4;
      if (which == 2) {
        const int b = mg0 >> 11, s0 = mg0 & 2047;
        const int h = ng >> 6, hd = ng & 63;
        bf16x4 pk;
#pragma unroll
        for (int r = 0; r < 4; r++) pk[r] = (__bf16)(acc[mi][ni][r] + bv);
        *(bf16x4*)(Out + (((b * Hh + h) * HD + hd) * Ss) + s0) = pk;
      } else {
#pragma unroll
        for (int r = 0; r < 4; r++) {
          float v = acc[mi][ni][r] + bv;
          if (which == 0) v *= SCL2;  // fold softmax scale+log2e into Q
          const int m = mg0 + r;
          const int b = m >> 11, s = m & 2047;
          const int h = ng >> 6, hd = ng & 63;
          Out[(((b * Hh + h) * Ss + s) * HD) + hd] = (__bf16)v;
        }
      }
    }
  }
}

// ---------------------------------------------------------------------------
// Out-proj GEMM (r9): C[4096,1024] fp32 = A @ Wo^T + bo. Tile 128x64, BK=64,
// grid (32,16) = 512 blocks (2/CU). 4 waves of 64x32. LDS [khalf][row][32]:
// row stride 64B + quad*16B col phases -> all 32 banks, conflict-free.
// ---------------------------------------------------------------------------
__global__ __launch_bounds__(256, 2) void gemm_out(
    const __bf16* __restrict__ A, const __bf16* __restrict__ W,
    const __bf16* __restrict__ bias, float* __restrict__ Out) {
  __shared__ __align__(16) __bf16 sA[2][128][32];  // 16 KB
  __shared__ __align__(16) __bf16 sB[2][64][32];   // 8 KB
  const int tid = threadIdx.x;
  const int lane = tid & 63;
  const int wid = tid >> 6;
  const int quad = lane >> 4;
  const int l15 = lane & 15;
  const int mBlock = blockIdx.x * 128;
  const int nBlock = blockIdx.y * 64;

  const int waveM = (wid >> 1) * 64;
  const int waveN = (wid & 1) * 32;

  f32x4 acc[4][2] = {};

  for (int k0 = 0; k0 < Dd; k0 += 64) {
    // A: 1024 chunks; c -> ks=c>>9, row=(c>>2)&127, j=(c&3)*8
#pragma unroll
    for (int j = 0; j < 4; j++) {
      const int c = j * 256 + tid;
      gl_lds16(A + (mBlock + ((c >> 2) & 127)) * Dd + k0 + (c >> 9) * 32 +
                   (c & 3) * 8,
               &sA[0][0][0] + c * 8);
    }
    // B: 512 chunks; c -> ks=c>>8, row=(c>>2)&63, j=(c&3)*8
#pragma unroll
    for (int j = 0; j < 2; j++) {
      const int c = j * 256 + tid;
      gl_lds16(W + (nBlock + ((c >> 2) & 63)) * Dd + k0 + (c >> 8) * 32 +
                   (c & 3) * 8,
               &sB[0][0][0] + c * 8);
    }
    __syncthreads();

#pragma unroll
    for (int ks = 0; ks < 2; ks++) {
      bf16x8 aF[4], bF[2];
#pragma unroll
      for (int mi = 0; mi < 4; mi++)
        aF[mi] = *(const bf16x8*)&sA[ks][waveM + mi * 16 + l15][quad * 8];
#pragma unroll
      for (int ni = 0; ni < 2; ni++)
        bF[ni] = *(const bf16x8*)&sB[ks][waveN + ni * 16 + l15][quad * 8];
#pragma unroll
      for (int mi = 0; mi < 4; mi++)
#pragma unroll
        for (int ni = 0; ni < 2; ni++)
          acc[mi][ni] = __builtin_amdgcn_mfma_f32_16x16x32_bf16(
              aF[mi], bF[ni], acc[mi][ni], 0, 0, 0);
    }
    __syncthreads();
  }

#pragma unroll
  for (int ni = 0; ni < 2; ni++) {
    const int ng = nBlock + waveN + ni * 16 + l15;
    const float bv = (float)bias[ng];
#pragma unroll
    for (int mi = 0; mi < 4; mi++) {
      const int mg0 = mBlock + waveM + mi * 16 + quad * 4;
#pragma unroll
      for (int r = 0; r < 4; r++)
        Out[(mg0 + r) * Dd + ng] = acc[mi][ni][r] + bv;
    }
  }
}

// ---------------------------------------------------------------------------
// Flash attention r9: as r8 (async dbuf, reg-exchange P) but K/V LDS stored
// as [quarter][row][16el] (32B row stride): A-frag b128 reads hit all 32
// banks (8 accesses each) -> conflict-free.
// K: sK[hd-quarter 4][kv 64][16] ; V: sV[kv-quarter 4][hd 64][16]
// flat idx: q*1024 + row*16 + j ; chunk c: q=c>>7, row=(c>>1)&63, j=(c&1)*8
// ---------------------------------------------------------------------------
__global__ __launch_bounds__(256, 4) void attn_fused(
    const __bf16* __restrict__ Qg, const __bf16* __restrict__ Kg,
    const __bf16* __restrict__ Vt, const float* __restrict__ Mf,
    __bf16* __restrict__ Og) {
  __shared__ __align__(16) union {
    __bf16 buf[2][8192];  // [buffer][K 4096 | V 4096]
    struct {
      float O[2][64][32];  // [qg][hd][q] kv-half-1 partial
      float L[2][32];
    } m;
  } sh;

  const int tid = threadIdx.x;
  const int lane = tid & 63;
  const int wid = tid >> 6;
  const int qg = wid & 1;
  const int kvh = wid >> 1;
  const int l31 = lane & 31;
  const int hi = lane >> 5;
  const int bh = blockIdx.y;
  const int b = bh >> 4;
  const int h = bh & 15;
  const int qw = blockIdx.x * 64 + qg * 32 + l31;  // this lane's q row

  const __bf16* Qp = Qg + (size_t)bh * Ss * HD;
  const __bf16* Kp = Kg + (size_t)bh * Ss * HD;
  const __bf16* Vp = Vt + (size_t)bh * HD * Ss;  // [hd][S]
  const float* Mrow = Mf + ((size_t)b * Ss + qw) * Ss + 32 * kvh + 4 * hi;

  // Q B-fragments in registers (B[k=hd][n=q]; lane: hd = 16k + 8hi + j).
  bf16x8 qf[4];
#pragma unroll
  for (int k = 0; k < 4; k++)
    qf[k] = *(const bf16x8*)(Qp + (size_t)qw * HD + k * 16 + hi * 8);

  const int cA = tid, cB = 256 + tid;
  // chunk c -> q=c>>7, row=(c>>1)&63, j=(c&1)*8 ; lds offset c*8
#define STAGE_KV(BI, KVS)                                                     \
  {                                                                           \
    __bf16* kb = sh.buf[BI];                                                  \
    gl_lds16(Kp + ((KVS) + ((cA >> 1) & 63)) * HD + (cA >> 7) * 16 +          \
                 (cA & 1) * 8, kb + cA * 8);                                  \
    gl_lds16(Kp + ((KVS) + ((cB >> 1) & 63)) * HD + (cB >> 7) * 16 +          \
                 (cB & 1) * 8, kb + cB * 8);                                  \
    __bf16* vb = sh.buf[BI] + 4096;                                           \
    gl_lds16(Vp + (size_t)((cA >> 1) & 63) * Ss + (KVS) + (cA >> 7) * 16 +    \
                 (cA & 1) * 8, vb + cA * 8);                                  \
    gl_lds16(Vp + (size_t)((cB >> 1) & 63) * Ss + (KVS) + (cB >> 7) * 16 +    \
                 (cB & 1) * 8, vb + cB * 8);                                  \
  }

  f32x16 o[2] = {};  // O^T partials: row=hd (C-layout), col=q
  f32x4 lacc = {0.f, 0.f, 0.f, 0.f};

  STAGE_KV(0, 0);  // prologue: tile 0 in flight (4 vm ops)

  for (int it = 0; it < 32; ++it) {
    const int kv0 = it * 64;
    const int bufc = it & 1;
    cfence();
    __builtin_amdgcn_s_barrier();  // A: all waves done reading buf[bufc^1]
    cfence();
    f32x4 mc[4];
#pragma unroll
    for (int g = 0; g < 4; g++) mc[g] = *(const f32x4*)(Mrow + kv0 + g * 8);
    cfence();  // pin issue order: mask(i) before stage(i+1)
    if (it < 31) {
      STAGE_KV(bufc ^ 1, kv0 + 64);  // stays in flight past barrier
      cfence();
      asm volatile("s_waitcnt vmcnt(8)" ::: "memory");  // drain tile i only
    } else {
      asm volatile("s_waitcnt vmcnt(4)" ::: "memory");  // drain tile 31
    }
    __builtin_amdgcn_s_barrier();  // B: everyone's tile-i data visible
    cfence();

    // S^T = K Q^T (A rows kv = 32*kvh + l31; k-step k = hd quarter).
    f32x16 sacc = {};
#pragma unroll
    for (int k = 0; k < 4; k++) {
      bf16x8 kf = *(const bf16x8*)(sh.buf[bufc] + k * 1024 +
                                   (kvh * 32 + l31) * 16 + hi * 8);
      sacc = __builtin_amdgcn_mfma_f32_32x32x16_bf16(kf, qf[k], sacc, 0, 0, 0);
    }

    // p = exp2(s + m*log2e); C-layout: reg g*4+r <-> kv = 32kvh+g*8+4hi+r.
    f32x4 sv[4];
#pragma unroll
    for (int g = 0; g < 4; g++)
#pragma unroll
      for (int r = 0; r < 4; r++)
        sv[g][r] = __builtin_amdgcn_exp2f(sacc[g * 4 + r] + mc[g][r] * LOG2E);
    lacc += (sv[0] + sv[1]) + (sv[2] + sv[3]);

    // P^T B-fragments via register exchange (hi halves swap alternate
    // 8-groups through lane^32).
    bf16x4 pk[4];
#pragma unroll
    for (int g = 0; g < 4; g++)
#pragma unroll
      for (int r = 0; r < 4; r++) pk[g][r] = (__bf16)sv[g][r];
    union pu { bf16x4 v; uint32_t w[2]; };
    pu s0, s1, r0, r1;
    s0.v = hi ? pk[0] : pk[1];
    s1.v = hi ? pk[2] : pk[3];
    r0.w[0] = __shfl_xor((int)s0.w[0], 32);
    r0.w[1] = __shfl_xor((int)s0.w[1], 32);
    r1.w[0] = __shfl_xor((int)s1.w[0], 32);
    r1.w[1] = __shfl_xor((int)s1.w[1], 32);
    bf16x8 pf[2];
    {
      bf16x4 lo0 = hi ? r0.v : pk[0], hi0 = hi ? pk[1] : r0.v;
      bf16x4 lo1 = hi ? r1.v : pk[2], hi1 = hi ? pk[3] : r1.v;
#pragma unroll
      for (int e = 0; e < 4; e++) {
        pf[0][e] = lo0[e]; pf[0][e + 4] = hi0[e];
        pf[1][e] = lo1[e]; pf[1][e + 4] = hi1[e];
      }
    }

    // O^T += V^T P^T (k-step k over wave's kv 32: quarter = kvh*2 + k).
#pragma unroll
    for (int k = 0; k < 2; k++)
#pragma unroll
      for (int hb = 0; hb < 2; hb++) {
        bf16x8 vf = *(const bf16x8*)(sh.buf[bufc] + 4096 +
                                     (kvh * 2 + k) * 1024 +
                                     (hb * 32 + l31) * 16 + hi * 8);
        o[hb] = __builtin_amdgcn_mfma_f32_32x32x16_bf16(vf, pf[k], o[hb],
                                                        0, 0, 0);
      }
  }

  float l = lacc[0] + lacc[1] + lacc[2] + lacc[3];
  l += __shfl_xor(l, 32);

  __syncthreads();  // all compute done; union switches to merge arrays
  // Merge kv-halves (plain add — no-max softmax has no rescale factor).
  if (kvh == 1) {
#pragma unroll
    for (int hb = 0; hb < 2; hb++)
#pragma unroll
      for (int r = 0; r < 16; r++) {
        const int hd = hb * 32 + (r & 3) + 8 * (r >> 2) + 4 * hi;
        sh.m.O[qg][hd][l31] = o[hb][r];
      }
    if (hi == 0) sh.m.L[qg][l31] = l;
  }
  __syncthreads();
  if (kvh == 0) {
#pragma unroll
    for (int hb = 0; hb < 2; hb++)
#pragma unroll
      for (int r = 0; r < 16; r++) {
        const int hd = hb * 32 + (r & 3) + 8 * (r >> 2) + 4 * hi;
        o[hb][r] += sh.m.O[qg][hd][l31];
      }
    l += sh.m.L[qg][l31];
    const float inv = 1.0f / l;
    __bf16* Ow = Og + (((size_t)b * Ss + qw) * Hh + h) * HD;
#pragma unroll
    for (int hb = 0; hb < 2; hb++)
#pragma unroll
      for (int g = 0; g < 4; g++) {
        const int hd = hb * 32 + g * 8 + 4 * hi;
        bf16x2 w0, w1;
        w0[0] = (__bf16)(o[hb][g * 4 + 0] * inv);
        w0[1] = (__bf16)(o[hb][g * 4 + 1] * inv);
        w1[0] = (__bf16)(o[hb][g * 4 + 2] * inv);
        w1[1] = (__bf16)(o[hb][g * 4 + 3] * inv);
        *(bf16x2*)(Ow + hd) = w0;
        *(bf16x2*)(Ow + hd + 2) = w1;
      }
  }
}

// ---------------------------------------------------------------------------
extern "C" void kernel_launch(void* const* d_in, const int* in_sizes, int n_in,
                              void* d_out, int out_size, void* d_ws,
                              size_t ws_size, hipStream_t stream) {
  if (ws_size < WS_NEED) return;

  __bf16* ws = (__bf16*)d_ws;
  const __bf16* hsC = ws + CAN_HS;
  const __bf16* WqC = ws + CAN_WQ;
  const __bf16* bqC = ws + CAN_BQ;
  const __bf16* WkC = ws + CAN_WK;
  const __bf16* bkC = ws + CAN_BK;
  const __bf16* WvC = ws + CAN_WV;
  const __bf16* bvC = ws + CAN_BV;
  const __bf16* WoC = ws + CAN_WO;
  const __bf16* boC = ws + CAN_BO;
  __bf16* Q = ws + CAN_END;
  __bf16* K = Q + TSZ;
  __bf16* V = K + TSZ;  // transposed layout [B,H,HD,S]
  __bf16* AW = V + TSZ;
  float* out = (float*)d_out;

  canon_kernel<<<2048, 256, 0, stream>>>(
      (const float*)d_in[0], (const float*)d_in[2], (const float*)d_in[3],
      (const float*)d_in[4], (const float*)d_in[5], (const float*)d_in[6],
      (const float*)d_in[7], (const float*)d_in[8], (const float*)d_in[9], ws);
  gemm_qkv<<<dim3(32, 24), 256, 0, stream>>>(hsC, WqC, WkC, WvC, bqC, bkC,
                                             bvC, Q, K, V);
  attn_fused<<<dim3(32, 32), 256, 0, stream>>>(Q, K, V, (const float*)d_in[1],
                                               AW);
  gemm_out<<<dim3(32, 16), 256, 0, stream>>>(AW, WoC, boC, out);
}